// Round 2
// baseline (3077.404 us; speedup 1.0000x reference)
//
#include <hip/hip_runtime.h>

#define CH   2048
#define COLS 128          // N*H = 4*32
#define WDIM 48
#define SL   (COLS*CH)    // 262144 elems per w-slice
#define NWG  256
#define TPB  512

using f32x16 = __attribute__((ext_vector_type(16))) float;
using bf16x8 = __attribute__((ext_vector_type(8))) short;

__device__ __forceinline__ short f2bf(float f) {
    union { float f; unsigned u; } v; v.f = f;
    unsigned u = v.u;
    u += 0x7fffu + ((u >> 16) & 1u);   // round-to-nearest-even
    return (short)(u >> 16);
}

// Wc bf16 from conv_w fp32 (C,C,1,9) taking [:,:,0,4]
__global__ __launch_bounds__(256) void prep_w(const float* __restrict__ cw,
                                              short* __restrict__ wcb) {
    int idx = blockIdx.x * 256 + threadIdx.x;          // o*2048 + c
    wcb[idx] = f2bf(cw[(size_t)idx * 9 + 4]);
}

// feature (N,C,H,W) -> x_t[w][col][c], col = n*32 + h
__global__ __launch_bounds__(256) void prep_x(const float* __restrict__ feat,
                                              float* __restrict__ xt) {
    int b = blockIdx.x;
    int col = b >> 5;            // 0..127
    int ct  = b & 31;            // c-tile (64 channels)
    int n = col >> 5, h = col & 31;
    int c0 = ct * 64;
    __shared__ float tile[64][49];
    int t = threadIdx.x;
    const float* base = feat + (((size_t)n * CH + c0) * 32 + h) * WDIM;
    #pragma unroll
    for (int it = 0; it < 3; ++it) {
        int id = it * 256 + t;             // 0..767
        int row = id / 12, w4 = id % 12;
        float4 v = *reinterpret_cast<const float4*>(base + (size_t)row * 1536 + w4 * 4);
        tile[row][w4*4+0] = v.x; tile[row][w4*4+1] = v.y;
        tile[row][w4*4+2] = v.z; tile[row][w4*4+3] = v.w;
    }
    __syncthreads();
    int c = t & 63, wq = t >> 6;
    #pragma unroll
    for (int it = 0; it < 12; ++it) {
        int w = it * 4 + wq;
        xt[((size_t)w * COLS + col) * CH + c0 + c] = tile[c][w];
    }
}

__global__ __launch_bounds__(256) void init0_k(const float* __restrict__ x0,
                                               float* __restrict__ fl0,
                                               short* __restrict__ fb0) {
    int i = blockIdx.x * 256 + threadIdx.x;
    float v = x0[i];
    fl0[i] = v;
    fb0[i] = f2bf(v);
}

// Persistent kernel: whole forward+backward recurrence, A resident in LDS.
__global__ __launch_bounds__(TPB, 1) void persist_k(
        const short* __restrict__ wcb, const float* __restrict__ xt,
        short* __restrict__ flbf, short* __restrict__ gbf,
        float* __restrict__ fl32, float* __restrict__ outt,
        const float* __restrict__ bias, const float* __restrict__ pa,
        unsigned* __restrict__ cnt)
{
    __shared__ short lA[32 * 2048];        // 128 KB, fragment-linear A panel
    __shared__ float red[8 * 8 * 64];      // 16 KB, two-phase K-split reduce

    int wg = blockIdx.x;
    int mg = wg >> 2, cg = wg & 3;         // wg%8 fixes cg per XCD -> B L2 reuse
    int m0 = mg * 32, n0 = cg * 32;
    int t = threadIdx.x;
    int wv = t >> 6, l = t & 63;
    int lrow = l & 31, lhalf = l >> 5;

    // Load A panel once: frag-linear so step-time ds_reads are lane-contiguous.
    {
        const short* src = wcb + (size_t)(m0 + lrow) * CH + wv * 256 + 8 * lhalf;
        short* dst = lA + wv * 8192 + l * 8;
        #pragma unroll
        for (int kk = 0; kk < 16; ++kk)
            *reinterpret_cast<bf16x8*>(dst + kk * 512) =
                *reinterpret_cast<const bf16x8*>(src + kk * 16);
    }

    // Per-thread epilogue constants (step-invariant).
    int rr = t >> 6, le = t & 63;
    int col = le & 31;
    int row0 = (rr & 3) + 8 * (rr >> 2) + 4 * (le >> 5);          // ri = rr
    int ri1 = 8 + rr;
    int row1 = (ri1 & 3) + 8 * (ri1 >> 2) + 4 * (le >> 5);
    int o0 = m0 + row0, o1 = m0 + row1;
    size_t off0 = (size_t)(n0 + col) * CH + o0;
    size_t off1 = (size_t)(n0 + col) * CH + o1;
    float b0 = bias[o0], b1 = bias[o1];
    float a = *pa;
    __syncthreads();

    const short* aL = lA + wv * 8192 + l * 8;
    unsigned tgt = 0;

    auto gbar = [&](unsigned target) {
        __syncthreads();
        if (t == 0) {
            __threadfence();
            __hip_atomic_fetch_add(cnt, 1u, __ATOMIC_RELAXED, __HIP_MEMORY_SCOPE_AGENT);
            int guard = 0;
            while (__hip_atomic_load(cnt, __ATOMIC_RELAXED, __HIP_MEMORY_SCOPE_AGENT) < target) {
                __builtin_amdgcn_s_sleep(2);
                if (++guard > (1 << 20)) break;    // bounded: fail visibly, not hang
            }
            __threadfence();
        }
        __syncthreads();
    };

    auto step = [&](const short* prevb, const float* res, float* outf, short* outb) {
        float r0 = res[off0], r1 = res[off1];       // prefetch residual early
        const short* bp = prevb + (size_t)(n0 + lrow) * CH + wv * 256 + 8 * lhalf;
        f32x16 acc = {};
        #pragma unroll
        for (int kk = 0; kk < 16; ++kk) {
            bf16x8 af = *reinterpret_cast<const bf16x8*>(aL + kk * 512);
            bf16x8 bq = *reinterpret_cast<const bf16x8*>(bp + kk * 16);
            acc = __builtin_amdgcn_mfma_f32_32x32x16_bf16(af, bq, acc, 0, 0, 0);
        }
        // phase 0: acc regs 0..7
        #pragma unroll
        for (int r = 0; r < 8; ++r) red[(wv * 8 + r) * 64 + l] = acc[r];
        __syncthreads();
        float s0 = 0.f;
        #pragma unroll
        for (int w2 = 0; w2 < 8; ++w2) s0 += red[(w2 * 8 + rr) * 64 + le];
        float v0 = s0 + b0; v0 = (v0 >= 0.f) ? v0 : a * v0; v0 += r0;
        outf[off0] = v0; outb[off0] = f2bf(v0);
        __syncthreads();
        // phase 1: acc regs 8..15
        #pragma unroll
        for (int r = 0; r < 8; ++r) red[(wv * 8 + r) * 64 + l] = acc[8 + r];
        __syncthreads();
        float s1 = 0.f;
        #pragma unroll
        for (int w2 = 0; w2 < 8; ++w2) s1 += red[(w2 * 8 + rr) * 64 + le];
        float v1 = s1 + b1; v1 = (v1 >= 0.f) ? v1 : a * v1; v1 += r1;
        outf[off1] = v1; outb[off1] = f2bf(v1);
    };

    // forward: fl[w] = prelu(Wc@fl[w-1]+b) + x[w]
    for (int w = 1; w < 48; ++w) {
        step(flbf + (size_t)(w - 1) * SL, xt + (size_t)w * SL,
             fl32 + (size_t)w * SL, flbf + (size_t)w * SL);
        tgt += NWG; gbar(tgt);
    }
    // out[47] = fl[47] (each WG copies its own tile; xt[47] already consumed)
    {
        const float* s = fl32 + (size_t)47 * SL;
        float* d = outt + (size_t)47 * SL;
        d[off0] = s[off0]; d[off1] = s[off1];
    }
    // backward: out[i] = prelu(Wc@state+b) + fl[i]
    const short* prev = flbf + (size_t)47 * SL;
    for (int i = 46; i >= 0; --i) {
        short* nxt = gbf + (size_t)(i & 1) * SL;
        step(prev, fl32 + (size_t)i * SL, outt + (size_t)i * SL, nxt);
        tgt += NWG; gbar(tgt);
        prev = nxt;
    }
}

// out_t[w][col][c] -> dout (N,C,H,W)
__global__ __launch_bounds__(256) void fin_t(const float* __restrict__ ot,
                                             float* __restrict__ dout) {
    int b = blockIdx.x;
    int col = b >> 5, ct = b & 31;
    int n = col >> 5, h = col & 31;
    int c0 = ct * 64;
    __shared__ float tile[48][65];
    int t = threadIdx.x;
    int c = t & 63, wq = t >> 6;
    #pragma unroll
    for (int it = 0; it < 12; ++it) {
        int w = it * 4 + wq;
        tile[w][c] = ot[((size_t)w * COLS + col) * CH + c0 + c];
    }
    __syncthreads();
    float* base = dout + (((size_t)n * CH + c0) * 32 + h) * WDIM;
    #pragma unroll
    for (int it = 0; it < 3; ++it) {
        int id = it * 256 + t;
        int row = id / 12, w4 = id % 12;
        float4 v;
        v.x = tile[w4*4+0][row]; v.y = tile[w4*4+1][row];
        v.z = tile[w4*4+2][row]; v.w = tile[w4*4+3][row];
        *reinterpret_cast<float4*>(base + (size_t)row * 1536 + w4 * 4) = v;
    }
}

extern "C" void kernel_launch(void* const* d_in, const int* in_sizes, int n_in,
                              void* d_out, int out_size, void* d_ws, size_t ws_size,
                              hipStream_t stream) {
    const float* feat = (const float*)d_in[0];
    const float* cw   = (const float*)d_in[1];
    const float* bias = (const float*)d_in[2];
    const float* pa   = (const float*)d_in[3];

    float* fl32 = (float*)d_out;                 // 48 fp32 slices live in d_out

    char* ws = (char*)d_ws;
    short* wcb  = (short*)(ws);                  // 8 MB   bf16 Wc
    float* xt   = (float*)(ws + 8388608);        // 48 MB  x_t (reused as out_t)
    short* flbf = (short*)(ws + 58720256);       // 24 MB  bf16 forward states
    short* gbf  = (short*)(ws + 83886080);       // 1 MB   bf16 backward ping-pong
    unsigned* cnt = (unsigned*)(ws + 84934656);  // barrier counter
    float* outt = xt;

    hipMemsetAsync(cnt, 0, 128, stream);
    prep_w<<<16384, 256, 0, stream>>>(cw, wcb);
    prep_x<<<4096, 256, 0, stream>>>(feat, xt);
    init0_k<<<1024, 256, 0, stream>>>(xt, fl32, flbf);   // fl[0] = x[0]

    persist_k<<<NWG, TPB, 0, stream>>>(wcb, xt, flbf, gbf, fl32, outt,
                                       bias, pa, cnt);

    fin_t<<<4096, 256, 0, stream>>>(outt, (float*)d_out);
}

// Round 3
// 675.548 us; speedup vs baseline: 4.5554x; 4.5554x over previous
//
#include <hip/hip_runtime.h>

#define CH   2048
#define COLS 128          // N*H = 4*32
#define WDIM 48
#define SL   (COLS*CH)    // 262144 elems per w-slice
#define NWG  256
#define TPB  512

using f32x16 = __attribute__((ext_vector_type(16))) float;
using bf16x8 = __attribute__((ext_vector_type(8))) short;

__device__ __forceinline__ short f2bf(float f) {
    union { float f; unsigned u; } v; v.f = f;
    unsigned u = v.u;
    u += 0x7fffu + ((u >> 16) & 1u);   // round-to-nearest-even
    return (short)(u >> 16);
}

// Wc bf16 from conv_w fp32 (C,C,1,9) taking [:,:,0,4]
__global__ __launch_bounds__(256) void prep_w(const float* __restrict__ cw,
                                              short* __restrict__ wcb) {
    int idx = blockIdx.x * 256 + threadIdx.x;          // o*2048 + c
    wcb[idx] = f2bf(cw[(size_t)idx * 9 + 4]);
}

// feature (N,C,H,W) -> x_t[w][col][c], col = n*32 + h
__global__ __launch_bounds__(256) void prep_x(const float* __restrict__ feat,
                                              float* __restrict__ xt) {
    int b = blockIdx.x;
    int col = b >> 5;            // 0..127
    int ct  = b & 31;            // c-tile (64 channels)
    int n = col >> 5, h = col & 31;
    int c0 = ct * 64;
    __shared__ float tile[64][49];
    int t = threadIdx.x;
    const float* base = feat + (((size_t)n * CH + c0) * 32 + h) * WDIM;
    #pragma unroll
    for (int it = 0; it < 3; ++it) {
        int id = it * 256 + t;             // 0..767
        int row = id / 12, w4 = id % 12;
        float4 v = *reinterpret_cast<const float4*>(base + (size_t)row * 1536 + w4 * 4);
        tile[row][w4*4+0] = v.x; tile[row][w4*4+1] = v.y;
        tile[row][w4*4+2] = v.z; tile[row][w4*4+3] = v.w;
    }
    __syncthreads();
    int c = t & 63, wq = t >> 6;
    #pragma unroll
    for (int it = 0; it < 12; ++it) {
        int w = it * 4 + wq;
        xt[((size_t)w * COLS + col) * CH + c0 + c] = tile[c][w];
    }
}

__global__ __launch_bounds__(256) void init0_k(const float* __restrict__ x0,
                                               float* __restrict__ fl0,
                                               short* __restrict__ fb0) {
    int i = blockIdx.x * 256 + threadIdx.x;
    float v = x0[i];
    fl0[i] = v;
    fb0[i] = f2bf(v);
}

// Persistent kernel, fence-free: state goes through IF$ (sc1 atomic stores),
// readers use ordinary cached loads (every slice has a fresh address).
__global__ __launch_bounds__(TPB, 1) void persist_k(
        const short* __restrict__ wcb, const float* __restrict__ xt,
        short* __restrict__ flbf, short* __restrict__ bwdb,
        float* __restrict__ fl32, float* __restrict__ outt,
        const float* __restrict__ bias, const float* __restrict__ pa,
        unsigned* __restrict__ cnt, int byp)
{
    __shared__ short lA[32 * 2048];        // 128 KB fragment-linear A panel
    __shared__ float red[8 * 8 * 64];      // 16 KB  two-phase K-split reduce
    __shared__ short sstage[32 * 32];      // 2 KB   state-store transpose

    int wg = blockIdx.x;
    int mg = wg >> 2, cg = wg & 3;         // XCD = wg&7 -> all WGs on an XCD share cg
    int m0 = mg * 32, n0 = cg * 32;
    int t = threadIdx.x;
    int wv = t >> 6, l = t & 63;
    int lrow = l & 31, lhalf = l >> 5;

    // Load A panel once (frag-linear: step-time ds_reads are lane-contiguous).
    {
        const short* src = wcb + (size_t)(m0 + lrow) * CH + wv * 256 + 8 * lhalf;
        short* dst = lA + wv * 8192 + l * 8;
        #pragma unroll
        for (int kk = 0; kk < 16; ++kk)
            *reinterpret_cast<bf16x8*>(dst + kk * 512) =
                *reinterpret_cast<const bf16x8*>(src + kk * 16);
    }

    // Step-invariant epilogue constants.
    int rr = t >> 6, le = t & 63;
    int col = le & 31;
    int row0 = (rr & 3) + 8 * (rr >> 2) + 4 * (le >> 5);
    int row1 = row0 + 16;
    int o0 = m0 + row0, o1 = m0 + row1;
    size_t off0 = (size_t)(n0 + col) * CH + o0;
    size_t off1 = (size_t)(n0 + col) * CH + o1;
    float b0 = bias[o0], b1 = bias[o1];
    float aP = *pa;
    int scol = t >> 4, sj = t & 15;                       // coalesced state store
    size_t soff = ((size_t)(n0 + scol) * CH + m0) / 2 + sj;  // int index
    __syncthreads();

    const short* aL = lA + wv * 8192 + l * 8;
    unsigned tgt = 0;
    unsigned* mycnt = cnt + cg * 32;       // per-cg counter, 128B apart

    auto gbar = [&]() {
        tgt += 64;                          // 64 WGs per cg-group
        __syncthreads();                    // drains vmcnt per wave (sc1 stores acked)
        if (t == 0) {
            __hip_atomic_fetch_add(mycnt, 1u, __ATOMIC_RELAXED, __HIP_MEMORY_SCOPE_AGENT);
            int guard = 0;
            while (__hip_atomic_load(mycnt, __ATOMIC_RELAXED, __HIP_MEMORY_SCOPE_AGENT) < tgt) {
                __builtin_amdgcn_s_sleep(1);
                if (++guard > (1 << 20)) break;   // fail visibly, never hang
            }
        }
        __syncthreads();
    };

    float v0 = 0.f, v1 = 0.f;
    auto step = [&](const short* prevb, const float* res, float* outf,
                    int* outb_i, bool bypass) {
        float r0 = res[off0], r1 = res[off1];
        const short* bp = prevb + (size_t)(n0 + lrow) * CH + wv * 256 + 8 * lhalf;
        f32x16 acc = {};
        if (!bypass) {
            #pragma unroll
            for (int kk = 0; kk < 16; ++kk) {
                bf16x8 bq = *reinterpret_cast<const bf16x8*>(bp + kk * 16);
                bf16x8 af = *reinterpret_cast<const bf16x8*>(aL + kk * 512);
                acc = __builtin_amdgcn_mfma_f32_32x32x16_bf16(af, bq, acc, 0, 0, 0);
            }
        } else {
            #pragma unroll
            for (int kk = 0; kk < 16; ++kk) {
                union { int i4[4]; bf16x8 v; } u;
                const int* ip = reinterpret_cast<const int*>(bp + kk * 16);
                #pragma unroll
                for (int j = 0; j < 4; ++j)
                    u.i4[j] = __hip_atomic_load(const_cast<int*>(ip) + j,
                                                __ATOMIC_RELAXED, __HIP_MEMORY_SCOPE_AGENT);
                bf16x8 af = *reinterpret_cast<const bf16x8*>(aL + kk * 512);
                acc = __builtin_amdgcn_mfma_f32_32x32x16_bf16(af, u.v, acc, 0, 0, 0);
            }
        }
        // K-split reduce, phase 0 (acc 0..7)
        #pragma unroll
        for (int r = 0; r < 8; ++r) red[(wv * 8 + r) * 64 + l] = acc[r];
        __syncthreads();
        float s0 = 0.f;
        #pragma unroll
        for (int w2 = 0; w2 < 8; ++w2) s0 += red[(w2 * 8 + rr) * 64 + le];
        v0 = s0 + b0; v0 = (v0 >= 0.f) ? v0 : aP * v0; v0 += r0;
        __syncthreads();
        // phase 1 (acc 8..15)
        #pragma unroll
        for (int r = 0; r < 8; ++r) red[(wv * 8 + r) * 64 + l] = acc[8 + r];
        __syncthreads();
        float s1 = 0.f;
        #pragma unroll
        for (int w2 = 0; w2 < 8; ++w2) s1 += red[(w2 * 8 + rr) * 64 + le];
        v1 = s1 + b1; v1 = (v1 >= 0.f) ? v1 : aP * v1; v1 += r1;
        outf[off0] = v0; outf[off1] = v1;          // ordinary (same-thread reuse only)
        if (outb_i) {
            sstage[col * 32 + row0] = f2bf(v0);
            sstage[col * 32 + row1] = f2bf(v1);
            __syncthreads();
            int sv = *reinterpret_cast<int*>(&sstage[scol * 32 + 2 * sj]);
            __hip_atomic_store(outb_i + soff, sv,
                               __ATOMIC_RELAXED, __HIP_MEMORY_SCOPE_AGENT);
        }
    };

    // forward: fl[w] = prelu(Wc@fl[w-1]+b) + x[w]
    for (int w = 1; w < 48; ++w) {
        step(flbf + (size_t)(w - 1) * SL, xt + (size_t)w * SL,
             fl32 + (size_t)w * SL,
             reinterpret_cast<int*>(flbf + (size_t)w * SL), false);
        gbar();
    }
    // out[47] = fl[47]: v0/v1 still hold this thread's fl[47] values
    outt[(size_t)47 * SL + off0] = v0;
    outt[(size_t)47 * SL + off1] = v1;
    // backward: out[i] = prelu(Wc@state+b) + fl[i]
    const short* prev = flbf + (size_t)47 * SL;
    for (int i = 46; i >= 0; --i) {
        short* nxt = bwdb + (size_t)(byp ? (i & 1) : i) * SL;
        step(prev, fl32 + (size_t)i * SL, outt + (size_t)i * SL,
             (i > 0) ? reinterpret_cast<int*>(nxt) : nullptr, byp != 0);
        if (i > 0) gbar();
        prev = nxt;
    }
}

// out_t[w][col][c] -> dout (N,C,H,W)
__global__ __launch_bounds__(256) void fin_t(const float* __restrict__ ot,
                                             float* __restrict__ dout) {
    int b = blockIdx.x;
    int col = b >> 5, ct = b & 31;
    int n = col >> 5, h = col & 31;
    int c0 = ct * 64;
    __shared__ float tile[48][65];
    int t = threadIdx.x;
    int c = t & 63, wq = t >> 6;
    #pragma unroll
    for (int it = 0; it < 12; ++it) {
        int w = it * 4 + wq;
        tile[w][c] = ot[((size_t)w * COLS + col) * CH + c0 + c];
    }
    __syncthreads();
    float* base = dout + (((size_t)n * CH + c0) * 32 + h) * WDIM;
    #pragma unroll
    for (int it = 0; it < 3; ++it) {
        int id = it * 256 + t;
        int row = id / 12, w4 = id % 12;
        float4 v;
        v.x = tile[w4*4+0][row]; v.y = tile[w4*4+1][row];
        v.z = tile[w4*4+2][row]; v.w = tile[w4*4+3][row];
        *reinterpret_cast<float4*>(base + (size_t)row * 1536 + w4 * 4) = v;
    }
}

extern "C" void kernel_launch(void* const* d_in, const int* in_sizes, int n_in,
                              void* d_out, int out_size, void* d_ws, size_t ws_size,
                              hipStream_t stream) {
    const float* feat = (const float*)d_in[0];
    const float* cw   = (const float*)d_in[1];
    const float* bias = (const float*)d_in[2];
    const float* pa   = (const float*)d_in[3];

    float* fl32 = (float*)d_out;                 // 48 fp32 slices live in d_out

    char* ws = (char*)d_ws;
    short* wcb  = (short*)(ws);                  // 8 MB    bf16 Wc
    float* xt   = (float*)(ws + 8388608);        // 48 MB   x_t (reused as out_t)
    short* flbf = (short*)(ws + 58720256);       // 24 MB   bf16 forward states (48 slices)
    unsigned* cnt = (unsigned*)(ws + 83886080);  // 1 KB    per-cg barrier counters
    short* bwdb = (short*)(ws + 83887104);       // 23.5 MB backward states (47 slices)
    float* outt = xt;

    // Full per-step bwd slices need ws >= ~108.6 MB; else ping-pong + bypass loads.
    const size_t needed_full = 83887104ull + 47ull * SL * 2;
    int byp = (ws_size < needed_full) ? 1 : 0;

    hipMemsetAsync(cnt, 0, 512, stream);
    prep_w<<<16384, 256, 0, stream>>>(cw, wcb);
    prep_x<<<4096, 256, 0, stream>>>(feat, xt);
    init0_k<<<1024, 256, 0, stream>>>(xt, fl32, flbf);   // fl[0] = x[0]

    persist_k<<<NWG, TPB, 0, stream>>>(wcb, xt, flbf, bwdb, fl32, outt,
                                       bias, pa, cnt, byp);

    fin_t<<<4096, 256, 0, stream>>>(outt, (float*)d_out);
}